// Round 11
// baseline (289.008 us; speedup 1.0000x reference)
//
#include <hip/hip_runtime.h>

// BatchAdaptiveConv2d via implicit GEMM on bf16 MFMA.
// out[b,o,y,x] = sum_{i,dy,dx} x[b,i,y+dy-1,x+dx-1] * W[i,o,dy,dx]*wadapt[b,i]
//               + bias[o]*badapt[b,o]
// R13 = R10 + 2-deep load pipeline (ONE change).
//  Falsified: occupancy(R5), VMEM rate(R9), traffic(R10), store order(R11),
//  DRAM granule(R12) — time pinned 96-120us, all pipes <20%, BW ~40% ceiling.
//  Surviving invariant: 1-deep prefetch. Per iter a CU bursts ~128KB of loads
//  whose vmcnt-wait has only ~1 compute phase (~1.5us) of cover, while the
//  chip-wide barrier-paced burst (~64MB) drains in ~10-15us -> every iter eats
//  the load-tail latency. Fix: PMa/PMb double prefetch buffers; batch issued
//  at t is consumed at t+2 (two compute+store phases of cover). Writes stay
//  1-step ahead: R10's proven slot schedule byte-identical.

#define B_    16
#define CIN   32
#define COUT  32
#define H_    256
#define W_    256
#define EMB2  512

#define XPX   66               // 64 + 2 halo pixels per LDS row
#define PXS   32               // ushorts per pixel (32 ch * bf16)
#define ROWS_ (XPX*PXS)        // 2112 ushorts per row-slot
#define NSLOT 8                // rolling window slots

using short8  = __attribute__((ext_vector_type(8))) short;
using float4v = __attribute__((ext_vector_type(4))) float;
using float4r = __attribute__((ext_vector_type(4))) float;

__device__ __forceinline__ unsigned short f2bf(float f) {
    unsigned u = __builtin_bit_cast(unsigned, f);
    u += 0x7FFFu + ((u >> 16) & 1u);      // RNE
    return (unsigned short)(u >> 16);
}
__device__ __forceinline__ unsigned pk2(float a, float b) {
    return (unsigned)f2bf(a) | ((unsigned)f2bf(b) << 16);
}

// ---------------- kernel 1: adapt coefficients ----------------
// ws[0..511] = wadapt[b][i]; ws[512..1023] = bias[o]*badapt[b][o]
__global__ __launch_bounds__(256) void adapt_kernel(
    const float* __restrict__ cond, const float* __restrict__ lpe,
    const float* __restrict__ wa_w, const float* __restrict__ wa_b,
    const float* __restrict__ ba_w, const float* __restrict__ ba_b,
    const float* __restrict__ bias, float* __restrict__ ws)
{
    __shared__ float iv[EMB2];
    __shared__ float partial[64][4];
    const int b = blockIdx.x;
    const int t = threadIdx.x;

    iv[t]       = cond[b*256 + t];
    iv[t + 256] = lpe[b*256 + t];
    __syncthreads();

    const int out  = t & 63;
    const int part = t >> 6;
    const float* row = (out < 32) ? (wa_w + out*EMB2) : (ba_w + (out-32)*EMB2);
    float s = 0.f;
    #pragma unroll 8
    for (int j = part*128; j < part*128 + 128; ++j) s += iv[j] * row[j];
    partial[out][part] = s;
    __syncthreads();

    if (t < 64) {
        float v = partial[t][0] + partial[t][1] + partial[t][2] + partial[t][3];
        if (t < 32) ws[b*32 + t] = v + wa_b[t];
        else {
            int o = t - 32;
            ws[512 + b*32 + o] = bias[o] * (v + ba_b[o]);
        }
    }
}

// ---------------- kernel 2: MFMA conv ----------------
// grid (W/64, H/32, B); block 256 = 4 waves. Wave w handles output row 4t+w.
__global__ __launch_bounds__(256, 2) void conv_kernel(
    const float* __restrict__ x, const float* __restrict__ weights,
    const float* __restrict__ ws, float* __restrict__ out)
{
    __shared__ __align__(16) unsigned short xbuf[NSLOT * ROWS_];   // 33792 B
    __shared__ __align__(16) unsigned short wbuf[9 * 2 * 64 * 8];  // 18432 B

    const int tid    = threadIdx.x;
    const int lane   = tid & 63;
    const int w      = tid >> 6;        // wave 0..3
    const int ln15   = lane & 15;
    const int kg     = lane >> 4;       // k-group 0..3
    const int xstrip = blockIdx.x * 64;
    const int ystrip = blockIdx.y * 32;
    const int b      = blockIdx.z;

    // ---- scaled weights -> wbuf[tap][ot][lane][j]: lane-consecutive 16B,
    //      conflict-free ds_read_b128 per (tap,ot).
    for (int idx = tid; idx < CIN*COUT*9; idx += 256) {
        int i   = idx / 288;
        int rem = idx - i*288;
        int o   = rem / 9;
        int tap = rem - o*9;
        float v = weights[idx] * ws[b*32 + i];
        wbuf[((tap*2 + (o>>4))*64 + ((i>>3)*16 + (o&15)))*8 + (i&7)] = f2bf(v);
    }

    // ---- helpers ----
    // main-px vector load: 8 channels x 4 consecutive px (8x dwordx4)
    auto ld_main = [&](int gy, int g, int q, float4r (&L)[8]) {
        if ((unsigned)gy < 256u) {
            const float* src = x + (((size_t)(b*CIN + g*8) << 16) + (gy << 8)
                                    + (xstrip + 4*q));
            #pragma unroll
            for (int j = 0; j < 8; ++j)
                L[j] = *(const float4r*)&src[(size_t)j << 16];
        } else {
            #pragma unroll
            for (int j = 0; j < 8; ++j) L[j] = float4r{0.f, 0.f, 0.f, 0.f};
        }
    };
    // register transpose (8ch x 4px -> 4 granules) + swizzled b128 writes.
    auto wr_main = [&](int r, int g, int q, const float4r (&L)[8]) {
        unsigned slot = (unsigned)(r + 1) & 7;
        #pragma unroll
        for (int n = 0; n < 4; ++n) {
            int k = (n + q) & 3;
            int p = 4*q + k + 1;                 // LDS pixel index 1..64
            uint4 pk;
            pk.x = pk2(L[0][k], L[1][k]);
            pk.y = pk2(L[2][k], L[3][k]);
            pk.z = pk2(L[4][k], L[5][k]);
            pk.w = pk2(L[6][k], L[7][k]);
            *(uint4*)&xbuf[slot*ROWS_ + p*PXS + ((g ^ ((p >> 1) & 3)) * 8)] = pk;
        }
    };
    // halo: one px, 8 channels, scalar loads (rare)
    auto load8 = [&](int g, int yy, int xx, float (&f)[8]) {
        if (((unsigned)yy < 256u) & ((unsigned)xx < 256u)) {
            const float* src = x + (((size_t)(b*CIN + g*8) << 16) + (yy << 8) + xx);
            #pragma unroll
            for (int j = 0; j < 8; ++j) f[j] = src[(size_t)j << 16];
        } else {
            #pragma unroll
            for (int j = 0; j < 8; ++j) f[j] = 0.f;
        }
    };
    auto packwrite = [&](int r, int p, int g, const float (&f)[8]) {
        unsigned slot = (unsigned)(r + 1) & 7;
        unsigned dst  = slot*ROWS_ + p*PXS + ((g ^ ((p >> 1) & 3)) * 8);
        uint4 pk;
        pk.x = pk2(f[0], f[1]); pk.y = pk2(f[2], f[3]);
        pk.z = pk2(f[4], f[5]); pk.w = pk2(f[6], f[7]);
        *(uint4*)&xbuf[dst] = pk;
    };

    // ---- prologue: direct-stage rows -1..4 (6 rows, slots 0..5) ----
    // main: 6 rows * 4 g * 16 quads = 384 chunks
    #pragma unroll
    for (int k2 = 0; k2 < 2; ++k2) {
        int ci = tid + k2*256;
        if (ci < 384) {
            int q = ci & 15, g = (ci >> 4) & 3, rr = ci >> 6;   // rr 0..5
            float4r L[8];
            ld_main(ystrip + rr - 1, g, q, L);
            wr_main(rr - 1, g, q, L);
        }
    }
    // halo: 6 rows * 4 g * 2 sides = 48 granules
    if (tid < 48) {
        int s = tid & 1, g = (tid >> 1) & 3, rr = tid >> 3;     // rr 0..5
        int p = s ? 65 : 0;
        float f[8];
        load8(g, ystrip + rr - 1, xstrip + p - 1, f);
        packwrite(rr - 1, p, g, f);
    }

    // ---- per-lane modulated bias (out = ot*16 + kg*4 + r) ----
    float bm[2][4];
    #pragma unroll
    for (int ot = 0; ot < 2; ++ot)
        #pragma unroll
        for (int r = 0; r < 4; ++r)
            bm[ot][r] = ws[512 + b*32 + ot*16 + kg*4 + r];

    // ---- 2-deep prefetch: two named buffer sets (static-indexed) ----
    float4r PMa[8], PMb[8];        // main: 8 ch x 4 px each
    float   PHa[8], PHb[8];        // halo: 8 ch x 1 px (tid<32 only)
    auto pf_issue_to = [&](float4r (&PM)[8], float (&PH)[8], int r0) {
        int q = tid & 15, g = (tid >> 4) & 3, rr = tid >> 6;    // rr 0..3
        ld_main(ystrip + r0 + rr, g, q, PM);
        if (tid < 32) {
            int s = tid & 1, hg = (tid >> 1) & 3, hr = tid >> 3; // hr 0..3
            int p = s ? 65 : 0;
            load8(hg, ystrip + r0 + hr, xstrip + p - 1, PH);
        }
    };
    auto pf_write_from = [&](float4r (&PM)[8], float (&PH)[8], int r0) {
        int q = tid & 15, g = (tid >> 4) & 3, rr = tid >> 6;
        wr_main(r0 + rr, g, q, PM);
        if (tid < 32) {
            int s = tid & 1, hg = (tid >> 1) & 3, hr = tid >> 3;
            int p = s ? 65 : 0;
            packwrite(r0 + hr, p, hg, PH);
        }
    };

    pf_issue_to(PMa, PHa, 5);                   // rows 5..8  -> consumed t=0
    pf_issue_to(PMb, PHb, 9);                   // rows 9..12 -> consumed t=1

    // prologue barrier: LDS writes visible; prefetch loads stay in flight.
    asm volatile("s_waitcnt lgkmcnt(0)" ::: "memory");
    __builtin_amdgcn_s_barrier();
    asm volatile("" ::: "memory");

    for (int tt = 0; tt < 4; ++tt) {
        #pragma unroll
        for (int half = 0; half < 2; ++half) {
            const int t    = 2*tt + half;       // 0..7
            const int orow = 4*t + w;           // this wave's output row
            const int gy   = ystrip + orow;

            float4v acc[4][2];
            #pragma unroll
            for (int c = 0; c < 4; ++c) {
                acc[c][0] = float4v{0.f, 0.f, 0.f, 0.f};
                acc[c][1] = float4v{0.f, 0.f, 0.f, 0.f};
            }

            #pragma unroll
            for (int dy = 0; dy < 3; ++dy) {
                // row orow+dy-1 lives in slot (orow+dy) & 7  (slot(r)=(r+1)&7)
                const int rowbase = ((orow + dy) & 7) * ROWS_;
                #pragma unroll
                for (int dx = 0; dx < 3; ++dx) {
                    const int tap = dy*3 + dx;
                    short8 a0 = *(const short8*)&wbuf[((tap*2 + 0)*64 + lane)*8];
                    short8 a1 = *(const short8*)&wbuf[((tap*2 + 1)*64 + lane)*8];
                    #pragma unroll
                    for (int c = 0; c < 4; ++c) {
                        int p = c*16 + dx + ln15;           // LDS pixel index
                        int a = rowbase + p*PXS + ((kg ^ ((p >> 1) & 3)) * 8);
                        short8 xf = *(const short8*)&xbuf[a];
                        acc[c][0] = __builtin_amdgcn_mfma_f32_16x16x32_bf16(
                                        a0, xf, acc[c][0], 0, 0, 0);
                        acc[c][1] = __builtin_amdgcn_mfma_f32_16x16x32_bf16(
                                        a1, xf, acc[c][1], 0, 0, 0);
                    }
                }
            }

            // post-compute barrier: all waves' LDS window reads done.
            asm volatile("s_waitcnt lgkmcnt(0)" ::: "memory");
            __builtin_amdgcn_s_barrier();
            asm volatile("" ::: "memory");

            // prefetch first: consume batch issued at t-2 (two phases of
            // cover), reissue same buffer for t+2.
            if (t < 7) {
                if (half == 0) {
                    pf_write_from(PMa, PHa, 4*t + 5);
                    if (t <= 4) pf_issue_to(PMa, PHa, 4*t + 13);
                } else {
                    pf_write_from(PMb, PHb, 4*t + 5);
                    if (t <= 4) pf_issue_to(PMb, PHb, 4*t + 13);
                }
            }

            asm volatile("" ::: "memory");

            // epilogue stores: D row(out) = kg*4 + r, col(pixel) = ln15
            #pragma unroll
            for (int c = 0; c < 4; ++c) {
                const int xcol = xstrip + c*16 + ln15;
                #pragma unroll
                for (int ot = 0; ot < 2; ++ot) {
                    const int obase = ot*16 + kg*4;
                    #pragma unroll
                    for (int r = 0; r < 4; ++r) {
                        out[((size_t)(b*COUT + obase + r)*256 + gy)*256 + xcol] =
                            acc[c][ot][r] + bm[ot][r];
                    }
                }
            }

            if (t < 7) {
                // staging barrier: ds_writes visible; loads NOT drained.
                asm volatile("s_waitcnt lgkmcnt(0)" ::: "memory");
                __builtin_amdgcn_s_barrier();
                asm volatile("" ::: "memory");
            }
        }
    }
}

extern "C" void kernel_launch(void* const* d_in, const int* in_sizes, int n_in,
                              void* d_out, int out_size, void* d_ws, size_t ws_size,
                              hipStream_t stream) {
    const float* x       = (const float*)d_in[0];
    const float* cond    = (const float*)d_in[1];
    const float* lpe     = (const float*)d_in[2];
    const float* weights = (const float*)d_in[3];
    const float* bias    = (const float*)d_in[4];
    const float* wa_w    = (const float*)d_in[5];
    const float* wa_b    = (const float*)d_in[6];
    const float* ba_w    = (const float*)d_in[7];
    const float* ba_b    = (const float*)d_in[8];
    float* outp = (float*)d_out;
    float* ws   = (float*)d_ws;    // 1024 floats: wadapt | bias*badapt

    adapt_kernel<<<dim3(B_), dim3(256), 0, stream>>>(
        cond, lpe, wa_w, wa_b, ba_w, ba_b, bias, ws);

    conv_kernel<<<dim3(W_/64, H_/32, B_), dim3(256), 0, stream>>>(
        x, weights, ws, outp);
}